// Round 3
// baseline (243.216 us; speedup 1.0000x reference)
//
#include <hip/hip_runtime.h>
#include <stdint.h>

// ---------------------------------------------------------------------------
// PatchEmbed + HMQConv2d fake-quant. ALL I/O fp32 (per reference dtypes).
//   s_x = max(max|x|,1e-8)/127 ; s_w = max(max|w|,1e-8)/127
//   out[b, gx*28+gy, d] = (sum_k qx*qw) * s_x*s_w + bias[d]
// GEMM: M=50176 (b,gx,gy), N=768 (d), K=192 (c*64+p*8+q).
// Integer codes (|q|<=127) fed to bf16 MFMA -> integer-exact accumulation.
// ws usage < 310 KB: slots + partials + Wq codes. A-quant fused into staging.
// ---------------------------------------------------------------------------

typedef short bf16x8 __attribute__((ext_vector_type(8)));  // 8 bf16 codes
using f32x4 = __attribute__((ext_vector_type(4))) float;

static __device__ __forceinline__ uint16_t f2bfbits(float f) {
  uint32_t u = __float_as_uint(f);
  u += 0x7FFFu + ((u >> 16) & 1u);   // RTNE (exact for ints <= 127)
  return (uint16_t)(u >> 16);
}

// quantize 2 floats -> 2 packed bf16 integer codes
static __device__ __forceinline__ uint32_t q2(float a, float b, float inv_s) {
  float qa = rintf(fminf(fmaxf(a * inv_s, -127.0f), 127.0f));
  float qb = rintf(fminf(fmaxf(b * inv_s, -127.0f), 127.0f));
  return (uint32_t)f2bfbits(qa) | ((uint32_t)f2bfbits(qb) << 16);
}

// ---- absmax stage 1 over x (fp32): per-block partial max ------------------
__global__ void absmax_x1_k(const float4* __restrict__ v, int n,
                            float* __restrict__ partials) {
  __shared__ float red[4];
  float m = 0.0f;
  for (int i = blockIdx.x * blockDim.x + threadIdx.x; i < n;
       i += gridDim.x * blockDim.x) {
    float4 u = v[i];
    m = fmaxf(m, fabsf(u.x)); m = fmaxf(m, fabsf(u.y));
    m = fmaxf(m, fabsf(u.z)); m = fmaxf(m, fabsf(u.w));
  }
#pragma unroll
  for (int off = 32; off > 0; off >>= 1) m = fmaxf(m, __shfl_down(m, off, 64));
  if ((threadIdx.x & 63) == 0) red[threadIdx.x >> 6] = m;
  __syncthreads();
  if (threadIdx.x == 0) {
    m = fmaxf(fmaxf(red[0], red[1]), fmaxf(red[2], red[3]));
    partials[blockIdx.x] = m;
  }
}

// ---- absmax stage 2: reduce 1024 partials -> s_x --------------------------
__global__ void absmax_x2_k(const float* __restrict__ partials,
                            float* __restrict__ s_out) {
  __shared__ float red[16];
  float m = partials[threadIdx.x];   // 1024 threads, 1024 partials
#pragma unroll
  for (int off = 32; off > 0; off >>= 1) m = fmaxf(m, __shfl_down(m, off, 64));
  if ((threadIdx.x & 63) == 0) red[threadIdx.x >> 6] = m;
  __syncthreads();
  if (threadIdx.x == 0) {
#pragma unroll
    for (int i = 1; i < 16; ++i) m = fmaxf(m, red[i]);
    s_out[0] = fmaxf(m, 1e-8f) * (1.0f / 127.0f);
  }
}

// ---- absmax over w (fp32, small): single block -> s_w ---------------------
__global__ void absmax_w_k(const float4* __restrict__ v, int n,
                           float* __restrict__ s_out) {
  __shared__ float red[16];
  float m = 0.0f;
  for (int i = threadIdx.x; i < n; i += blockDim.x) {
    float4 u = v[i];
    m = fmaxf(m, fabsf(u.x)); m = fmaxf(m, fabsf(u.y));
    m = fmaxf(m, fabsf(u.z)); m = fmaxf(m, fabsf(u.w));
  }
#pragma unroll
  for (int off = 32; off > 0; off >>= 1) m = fmaxf(m, __shfl_down(m, off, 64));
  if ((threadIdx.x & 63) == 0) red[threadIdx.x >> 6] = m;
  __syncthreads();
  if (threadIdx.x == 0) {
#pragma unroll
    for (int i = 1; i < 16; ++i) m = fmaxf(m, red[i]);
    s_out[0] = fmaxf(m, 1e-8f) * (1.0f / 127.0f);
  }
}

// ---- quantize w: fp32 [768*192] -> bf16 codes [768][192] ------------------
// flat order d*192 + c*64 + p*8 + q is already the GEMM k-order.
__global__ void quant_w_k(const float4* __restrict__ w, uint2* __restrict__ Wq,
                          const float* __restrict__ slots, int n) {
  int tid = blockIdx.x * blockDim.x + threadIdx.x;
  if (tid >= n) return;
  float inv = 1.0f / slots[1];
  float4 u = w[tid];
  Wq[tid] = make_uint2(q2(u.x, u.y, inv), q2(u.z, u.w, inv));
}

// ---------------------------------------------------------------------------
// GEMM with fused A quantization. C[M,768] = Aq[M,192] * Wq[768,192]^T.
// mfma_f32_16x16x32_bf16 verified layouts (m89/m120):
//   A frag: A[m = lane&15][k = (lane>>4)*8 + j]
//   B frag: W[n = lane&15][k = (lane>>4)*8 + j]   (Wq is [n][k])
//   D:      row = (lane>>4)*4 + reg, col = lane&15
// ---------------------------------------------------------------------------
#define BM  128
#define BN  128
#define LDP 72   // padded LDS stride: 2-way bank alias only (free per m136)

__global__ __launch_bounds__(256) void gemm_k(
    const float4* __restrict__ x4, const uint16_t* __restrict__ Wq,
    const float* __restrict__ bias, const float* __restrict__ slots,
    float* __restrict__ out) {
  __shared__ uint16_t As[BM * LDP];
  __shared__ uint16_t Ws[BN * LDP];

  const int m0   = blockIdx.y * BM;
  const int n0   = blockIdx.x * BN;
  const int tid  = threadIdx.x;
  const int lane = tid & 63;
  const int wid  = tid >> 6;
  const int wm   = wid >> 1;   // 0..1
  const int wn   = wid & 1;    // 0..1
  const int r0   = tid >> 3;   // 0..31 (row group)
  const int c8   = tid & 7;    // 0..7  (== p, row within 8x8 patch)
  const int lm   = lane & 15;
  const int lq   = lane >> 4;

  const float sx = slots[0];
  const float sw = slots[1];
  const float inv_sx = 1.0f / sx;

  // float4 index of x[(b, c=0, gx*8+c8, gy*8)] for row m = b*784+gx*28+gy:
  //   fp32 idx = ((b*3)*224 + gx*8 + c8)*224 + gy*8 ; /4 for float4
  int xbase[4];
#pragma unroll
  for (int i = 0; i < 4; ++i) {
    int m  = m0 + r0 + i * 32;
    int b  = m / 784;
    int rr = m - b * 784;
    int gx = rr / 28;
    int gy = rr - gx * 28;
    xbase[i] = (b * 672 + gx * 8 + c8) * 56 + gy * 2;
  }

  f32x4 acc[4][4] = {};

  for (int kc = 0; kc < 3; ++kc) {
#pragma unroll
    for (int i = 0; i < 4; ++i) {
      int row = r0 + i * 32;
      // channel kc: + kc*224*224/4 = kc*12544 float4s
      float4 a0 = x4[xbase[i] + kc * 12544];
      float4 a1 = x4[xbase[i] + kc * 12544 + 1];
      uint4 q;
      q.x = q2(a0.x, a0.y, inv_sx);
      q.y = q2(a0.z, a0.w, inv_sx);
      q.z = q2(a1.x, a1.y, inv_sx);
      q.w = q2(a1.z, a1.w, inv_sx);
      *(uint4*)(&As[row * LDP + c8 * 8]) = q;
      uint4 vb = *(const uint4*)(Wq + (size_t)(n0 + row) * 192 + kc * 64 + c8 * 8);
      *(uint4*)(&Ws[row * LDP + c8 * 8]) = vb;
    }
    __syncthreads();

#pragma unroll
    for (int kk = 0; kk < 2; ++kk) {
      const int colk = kk * 32 + lq * 8;
      bf16x8 af[4], bfr[4];
#pragma unroll
      for (int t = 0; t < 4; ++t) {
        af[t]  = *(const bf16x8*)(&As[(wm * 64 + t * 16 + lm) * LDP + colk]);
        bfr[t] = *(const bf16x8*)(&Ws[(wn * 64 + t * 16 + lm) * LDP + colk]);
      }
#pragma unroll
      for (int tm = 0; tm < 4; ++tm)
#pragma unroll
        for (int tn = 0; tn < 4; ++tn)
          acc[tm][tn] = __builtin_amdgcn_mfma_f32_16x16x32_bf16(
              af[tm], bfr[tn], acc[tm][tn], 0, 0, 0);
    }
    __syncthreads();
  }

  const float scale = sx * sw;
#pragma unroll
  for (int tn = 0; tn < 4; ++tn) {
    int col = n0 + wn * 64 + tn * 16 + lm;
    float bv = bias[col];
#pragma unroll
    for (int tm = 0; tm < 4; ++tm) {
      int rbase = m0 + wm * 64 + tm * 16 + lq * 4;
#pragma unroll
      for (int r = 0; r < 4; ++r) {
        out[(size_t)(rbase + r) * 768 + col] = acc[tm][tn][r] * scale + bv;
      }
    }
  }
}

// ---------------------------------------------------------------------------

extern "C" void kernel_launch(void* const* d_in, const int* in_sizes, int n_in,
                              void* d_out, int out_size, void* d_ws, size_t ws_size,
                              hipStream_t stream) {
  const float4* x = (const float4*)d_in[0];      // 9,633,792 fp32
  const float4* w = (const float4*)d_in[1];      //   147,456 fp32
  const float* bias = (const float*)d_in[2];     //       768 fp32
  float* out = (float*)d_out;                    // 38,535,168 fp32

  char* ws = (char*)d_ws;
  float* slots    = (float*)ws;             // [0]=s_x, [1]=s_w
  float* partials = (float*)(ws + 256);     // 1024 floats
  uint16_t* Wq    = (uint16_t*)(ws + 8192); // 294,912 B of bf16 codes

  const int nx4 = 9633792 / 4;   // 2,408,448 float4
  const int nw4 = 147456 / 4;    //    36,864 float4

  absmax_x1_k<<<1024, 256, 0, stream>>>(x, nx4, partials);
  absmax_x2_k<<<1, 1024, 0, stream>>>(partials, slots + 0);
  absmax_w_k<<<1, 1024, 0, stream>>>(w, nw4, slots + 1);
  quant_w_k<<<144, 256, 0, stream>>>(w, (uint2*)Wq, slots, nw4);
  gemm_k<<<dim3(6, 392), 256, 0, stream>>>(x, Wq, bias, slots, out);
}